// Round 5
// baseline (236.271 us; speedup 1.0000x reference)
//
#include <hip/hip_runtime.h>
#include <cstdint>
#include <cstddef>

// Problem constants (match reference setup_inputs)
#define NB   8               // batch
#define RDIM 1024
#define CDIM 1024
#define PB   (RDIM * CDIM)   // pixels per batch = 1M
#define NI   16              // MAX_INSTANCES

// Cluster-kernel geometry: 1024-thread blocks, 8 rows/block, LDS-staged
// gather window of 8 + 2*26 = 60 rows (61440 B). Margin 26 covers |offset|
// up to 26 px; N(0,4) offsets max ~23 over 8.4M samples; larger offsets take
// the (execz-skipped) global fallback, so correctness holds for any input.
#define MARG  26
#define BROWS 8
#define WROWS (BROWS + 2 * MARG)   // 60

typedef int     i32x4 __attribute__((ext_vector_type(4)));
typedef float   f32x4 __attribute__((ext_vector_type(4)));
typedef uint8_t u8x4  __attribute__((ext_vector_type(4)));

// ---------------------------------------------------------------------------
// Kernel A: per-(batch,instance) valid-pixel histogram via wave-ballot
// popcount (no per-pixel atomics) + pack gt|mask into a uint8 map (8 MB).
// ~13-15 us, near its 64 MB read floor. Unchanged.
// ---------------------------------------------------------------------------
__global__ __launch_bounds__(256) void count_pack_kernel(
    const int* __restrict__ nz, const int* __restrict__ gt,
    uint8_t* __restrict__ gt8, int* __restrict__ counts)
{
    __shared__ unsigned s[4 * NI];           // 4 waves x 16 bins
    const int b    = blockIdx.y;
    const int lane = threadIdx.x & 63;
    const int wv   = threadIdx.x >> 6;
    const i32x4* nzb = (const i32x4*)(nz + (size_t)b * PB);
    const i32x4* gtb = (const i32x4*)(gt + (size_t)b * PB);
    u8x4* g8b = gt8 ? (u8x4*)(gt8 + (size_t)b * PB) : nullptr;

    unsigned wc[NI];
    #pragma unroll
    for (int k = 0; k < NI; ++k) wc[k] = 0;

    const int n4 = PB / 4;
    for (int i = blockIdx.x * blockDim.x + threadIdx.x; i < n4;
         i += gridDim.x * blockDim.x) {
        i32x4 nzv = __builtin_nontemporal_load(&nzb[i]);
        i32x4 gv  = __builtin_nontemporal_load(&gtb[i]);
        int gm[4];
        u8x4 o;
        #pragma unroll
        for (int j = 0; j < 4; ++j) {
            const int g = gv[j];
            const int m = (nzv[j] > 0) & (g > 0);
            gm[j] = m ? g : 0;                       // 0 = contributes nowhere
            o[j]  = (uint8_t)(g | (m << 7));
        }
        if (g8b) g8b[i] = o;                          // cached store (B re-reads)
        #pragma unroll
        for (int j = 0; j < 4; ++j) {
            #pragma unroll
            for (int id = 1; id < NI; ++id) {
                unsigned long long bal = __ballot(gm[j] == id);
                wc[id] += (unsigned)__popcll(bal);    // wave-uniform scalar add
            }
        }
    }
    if (lane == 0) {
        #pragma unroll
        for (int id = 1; id < NI; ++id) s[wv * NI + id] = wc[id];
    }
    __syncthreads();
    if (threadIdx.x >= 1 && threadIdx.x < NI) {
        unsigned sum = s[threadIdx.x] + s[NI + threadIdx.x] +
                       s[2 * NI + threadIdx.x] + s[3 * NI + threadIdx.x];
        if (sum) atomicAdd((unsigned*)&counts[b * NI + threadIdx.x], sum);
    }
}

// ---------------------------------------------------------------------------
// Kernel B (packed path): LDS-staged gather, PLAIN loads/stores.
// R5 change: all NT hints removed — the measured 6.29 TB/s copy ceiling and
// the 6.8 TB/s harness fills both use plain cached accesses; NT stores force
// the full 100 MB write through the bypass path in-kernel. Everything else
// (LDS window gather, XCD band swizzle, 2 quads/thread) unchanged from R4.
// rintf == round-half-to-even == np.round (critical for `agree` parity).
// ---------------------------------------------------------------------------
__global__ __launch_bounds__(1024, 8) void cluster_lds_kernel(
    const float* __restrict__ pp, const float* __restrict__ op,
    const uint8_t* __restrict__ gt8,
    const int* __restrict__ counts, float* __restrict__ out)
{
    __shared__ __align__(16) uint8_t sg[WROWS * CDIM];   // 61440 B
    __shared__ float inv[NI];

    const int b   = blockIdx.y;
    const int tid = threadIdx.x;

    // XCD band swizzle (gridDim.x = 128, 8 XCDs -> 16-block bands)
    const int nbx = gridDim.x;
    const int p0  = blockIdx.x;
    const int bx  = (p0 & 7) * (nbx >> 3) + (p0 >> 3);

    const int r0 = bx * BROWS;
    const int w0 = (r0 - MARG) > 0 ? (r0 - MARG) : 0;
    int w1 = r0 + BROWS + MARG; if (w1 > RDIM) w1 = RDIM;

    const uint8_t* g8b = gt8 + (size_t)b * PB;

    if (tid < NI) {
        int c = counts[b * NI + tid];
        inv[tid] = 1.0f / (float)(c > 1 ? c : 1);
    }
    // stage rows [w0, w1) of the map (16 B per thread-iteration, coalesced)
    {
        const int nb16 = ((w1 - w0) << 10) >> 4;
        const i32x4* src = (const i32x4*)(g8b + ((size_t)w0 << 10));
        i32x4* dst = (i32x4*)sg;
        for (int k = tid; k < nb16; k += 1024) dst[k] = src[k];
    }
    __syncthreads();

    const f32x4* ppb = (const f32x4*)(pp + (size_t)b * PB);
    const f32x4* dyb = (const f32x4*)(op + (size_t)b * 2 * PB);
    const f32x4* dxb = dyb + PB / 4;
    f32x4* pwb  = (f32x4*)(out + (size_t)b * PB);
    f32x4* owyb = (f32x4*)(out + (size_t)NB * PB + (size_t)b * 2 * PB);
    f32x4* owxb = owyb + PB / 4;

    const int q0 = bx * (BROWS * CDIM / 4) + tid;   // first of 2 quads

    // issue all streaming loads up front (plain, cached)
    f32x4 dyv[2], dxv[2], ppv[2];
    #pragma unroll
    for (int u = 0; u < 2; ++u) dyv[u] = dyb[q0 + 1024 * u];
    #pragma unroll
    for (int u = 0; u < 2; ++u) dxv[u] = dxb[q0 + 1024 * u];
    #pragma unroll
    for (int u = 0; u < 2; ++u) ppv[u] = ppb[q0 + 1024 * u];

    // own map bytes from LDS (own rows are always inside the window)
    uint32_t own[2];
    #pragma unroll
    for (int u = 0; u < 2; ++u) {
        const int pix = (q0 + 1024 * u) * 4;
        const int r = pix >> 10, c = pix & (CDIM - 1);
        own[u] = *(const uint32_t*)&sg[((r - w0) << 10) + c];
    }

    #pragma unroll
    for (int u = 0; u < 2; ++u) {
        const int   pix = (q0 + 1024 * u) * 4;
        const float rf  = (float)(pix >> 10);
        const float cf0 = (float)(pix & (CDIM - 1));
        f32x4 pwv, oyv, oxv;
        #pragma unroll
        for (int j = 0; j < 4; ++j) {
            const int gbyte = (own[u] >> (8 * j)) & 0xff;
            const int gs = gbyte & 0x7f;
            const int ms = gbyte >> 7;
            const float dy = dyv[u][j], dx = dxv[u][j];
            const float tyf = fminf(fmaxf(rintf(rf + dy), 0.0f), (float)(RDIM - 1));
            const float txf = fminf(fmaxf(rintf(cf0 + (float)j + dx), 0.0f), (float)(CDIM - 1));
            const int ty = (int)tyf, tx = (int)txf;
            int tg;
            if (ty >= w0 && ty < w1)
                tg = sg[((ty - w0) << 10) + tx] & 0x7f;     // LDS gather
            else
                tg = g8b[(ty << 10) + tx] & 0x7f;           // rare fallback
            const float w  = ms ? inv[gs] : 0.0f;
            const float aw = (ms && (tg == gs)) ? w : 0.0f;
            pwv[j] = w * (1.0f / (1.0f + __expf(-ppv[u][j])));
            oyv[j] = aw * dy;
            oxv[j] = aw * dx;
        }
        pwb [q0 + 1024 * u] = pwv;     // plain cached stores
        owyb[q0 + 1024 * u] = oyv;
        owxb[q0 + 1024 * u] = oxv;
    }
}

// ---------------------------------------------------------------------------
// Fallback (ws too small for the packed map): direct kernel.
// ---------------------------------------------------------------------------
__global__ __launch_bounds__(256) void cluster_plain_kernel(
    const float* __restrict__ pp, const float* __restrict__ op,
    const int* __restrict__ nz, const int* __restrict__ gt,
    const int* __restrict__ counts, float* __restrict__ out)
{
    __shared__ float inv[NI];
    const int b = blockIdx.y;
    if (threadIdx.x < NI) {
        int c = counts[b * NI + threadIdx.x];
        inv[threadIdx.x] = 1.0f / (float)(c > 1 ? c : 1);
    }
    __syncthreads();
    const int i = blockIdx.x * blockDim.x + threadIdx.x;

    const int*   gtb = gt + (size_t)b * PB;
    const int*   nzb = nz + (size_t)b * PB;
    const f32x4* ppb = (const f32x4*)(pp + (size_t)b * PB);
    const f32x4* dyb = (const f32x4*)(op + (size_t)b * 2 * PB);
    const f32x4* dxb = dyb + PB / 4;
    f32x4* pwb  = (f32x4*)(out + (size_t)b * PB);
    f32x4* owyb = (f32x4*)(out + (size_t)NB * PB + (size_t)b * 2 * PB);
    f32x4* owxb = owyb + PB / 4;

    const int   pix = i * 4;
    const float rf  = (float)(pix >> 10);
    const float cf0 = (float)(pix & (CDIM - 1));
    f32x4 ppv = ppb[i], dyv = dyb[i], dxv = dxb[i];
    i32x4 gv = *((const i32x4*)gtb + i), nzv = *((const i32x4*)nzb + i);

    f32x4 pwv, oyv, oxv;
    #pragma unroll
    for (int j = 0; j < 4; ++j) {
        const int gs = gv[j];
        const int ms = (nzv[j] > 0) & (gs > 0);
        float ty = fminf(fmaxf(rintf(rf + dyv[j]), 0.0f), (float)(RDIM - 1));
        float tx = fminf(fmaxf(rintf(cf0 + (float)j + dxv[j]), 0.0f), (float)(CDIM - 1));
        const int tg = gtb[(int)ty * CDIM + (int)tx];
        const float w  = ms ? inv[gs] : 0.0f;
        const float aw = (ms && (tg == gs)) ? w : 0.0f;
        pwv[j] = w * (1.0f / (1.0f + __expf(-ppv[j])));
        oyv[j] = aw * dyv[j];
        oxv[j] = aw * dxv[j];
    }
    pwb[i] = pwv; owyb[i] = oyv; owxb[i] = oxv;
}

extern "C" void kernel_launch(void* const* d_in, const int* in_sizes, int n_in,
                              void* d_out, int out_size, void* d_ws, size_t ws_size,
                              hipStream_t stream) {
    // setup_inputs order: non_zeros_map, pixel_pred, offset_pred, pixel_gt
    const int*   nz = (const int*)d_in[0];
    const float* pp = (const float*)d_in[1];
    const float* op = (const float*)d_in[2];
    const int*   gt = (const int*)d_in[3];
    float* out = (float*)d_out;

    int* counts = (int*)d_ws;                       // NB*NI ints at ws[0]
    const size_t need = 1024 + (size_t)NB * PB;     // counts (padded) + gt8 map
    const bool packed = ws_size >= need;
    uint8_t* gt8 = packed ? (uint8_t*)d_ws + 1024 : nullptr;

    hipMemsetAsync(counts, 0, NB * NI * sizeof(int), stream);

    dim3 blkA(256), grdA(256, NB);
    count_pack_kernel<<<grdA, blkA, 0, stream>>>(nz, gt, gt8, counts);

    if (packed) {
        cluster_lds_kernel<<<dim3(128, NB), dim3(1024), 0, stream>>>(pp, op, gt8, counts, out);
    } else {
        cluster_plain_kernel<<<dim3(1024, NB), dim3(256), 0, stream>>>(pp, op, nz, gt, counts, out);
    }
}

// Round 6
// 228.395 us; speedup vs baseline: 1.0345x; 1.0345x over previous
//
#include <hip/hip_runtime.h>
#include <cstdint>
#include <cstddef>

// Problem constants (match reference setup_inputs)
#define NB   8               // batch
#define RDIM 1024
#define CDIM 1024
#define PB   (RDIM * CDIM)   // pixels per batch = 1M
#define NI   16              // MAX_INSTANCES

// Cluster geometry: 1024-thread blocks, 16 rows/block, LDS-staged gather
// window of 16 + 2*23 = 62 rows (63488 B < 64 KB -> 2 blocks/CU).
// Margin 23: offsets are 4*N(0,1); P(any |dy|>23.5 over 8.4M samples) ~ 3%,
// and out-of-window targets take the (execz-skipped) global fallback, so
// correctness holds for arbitrary offsets. Amplification 62/16 = 3.9x
// (vs 7.5x at BROWS=8): staging traffic 61 -> 31 MB.
#define MARG  23
#define BROWS 16
#define WROWS (BROWS + 2 * MARG)   // 62

typedef int     i32x4 __attribute__((ext_vector_type(4)));
typedef float   f32x4 __attribute__((ext_vector_type(4)));
typedef uint8_t u8x4  __attribute__((ext_vector_type(4)));

// ---------------------------------------------------------------------------
// Kernel A: per-(batch,instance) valid-pixel histogram via wave-ballot
// popcount (no per-pixel atomics) + pack gt|mask into a uint8 map (8 MB).
// ~13-15 us, near its 64 MB read floor. Unchanged.
// ---------------------------------------------------------------------------
__global__ __launch_bounds__(256) void count_pack_kernel(
    const int* __restrict__ nz, const int* __restrict__ gt,
    uint8_t* __restrict__ gt8, int* __restrict__ counts)
{
    __shared__ unsigned s[4 * NI];           // 4 waves x 16 bins
    const int b    = blockIdx.y;
    const int lane = threadIdx.x & 63;
    const int wv   = threadIdx.x >> 6;
    const i32x4* nzb = (const i32x4*)(nz + (size_t)b * PB);
    const i32x4* gtb = (const i32x4*)(gt + (size_t)b * PB);
    u8x4* g8b = gt8 ? (u8x4*)(gt8 + (size_t)b * PB) : nullptr;

    unsigned wc[NI];
    #pragma unroll
    for (int k = 0; k < NI; ++k) wc[k] = 0;

    const int n4 = PB / 4;
    for (int i = blockIdx.x * blockDim.x + threadIdx.x; i < n4;
         i += gridDim.x * blockDim.x) {
        i32x4 nzv = __builtin_nontemporal_load(&nzb[i]);
        i32x4 gv  = __builtin_nontemporal_load(&gtb[i]);
        int gm[4];
        u8x4 o;
        #pragma unroll
        for (int j = 0; j < 4; ++j) {
            const int g = gv[j];
            const int m = (nzv[j] > 0) & (g > 0);
            gm[j] = m ? g : 0;                       // 0 = contributes nowhere
            o[j]  = (uint8_t)(g | (m << 7));
        }
        if (g8b) g8b[i] = o;                          // cached store (B re-reads)
        #pragma unroll
        for (int j = 0; j < 4; ++j) {
            #pragma unroll
            for (int id = 1; id < NI; ++id) {
                unsigned long long bal = __ballot(gm[j] == id);
                wc[id] += (unsigned)__popcll(bal);    // wave-uniform scalar add
            }
        }
    }
    if (lane == 0) {
        #pragma unroll
        for (int id = 1; id < NI; ++id) s[wv * NI + id] = wc[id];
    }
    __syncthreads();
    if (threadIdx.x >= 1 && threadIdx.x < NI) {
        unsigned sum = s[threadIdx.x] + s[NI + threadIdx.x] +
                       s[2 * NI + threadIdx.x] + s[3 * NI + threadIdx.x];
        if (sum) atomicAdd((unsigned*)&counts[b * NI + threadIdx.x], sum);
    }
}

// ---------------------------------------------------------------------------
// Kernel B (packed path): LDS-staged gather, NT streaming (R4 recipe, which
// measured ~6 us faster than plain), 16 rows/block (halved staging
// amplification), 4 quads/thread processed in two halves to keep live VGPRs
// under the 64-reg bound required for 2 blocks/CU (launch_bounds 1024,8).
// rintf == round-half-to-even == np.round (critical for `agree` parity).
// ---------------------------------------------------------------------------
__global__ __launch_bounds__(1024, 8) void cluster_lds_kernel(
    const float* __restrict__ pp, const float* __restrict__ op,
    const uint8_t* __restrict__ gt8,
    const int* __restrict__ counts, float* __restrict__ out)
{
    __shared__ __align__(16) uint8_t sg[WROWS * CDIM];   // 63488 B
    __shared__ float inv[NI];

    const int b   = blockIdx.y;
    const int tid = threadIdx.x;

    // XCD band swizzle (gridDim.x = 64, 8 XCDs -> 8-block bands)
    const int p0  = blockIdx.x;
    const int bx  = (p0 & 7) * 8 + (p0 >> 3);

    const int r0 = bx * BROWS;
    const int w0 = (r0 - MARG) > 0 ? (r0 - MARG) : 0;
    int w1 = r0 + BROWS + MARG; if (w1 > RDIM) w1 = RDIM;

    const uint8_t* g8b = gt8 + (size_t)b * PB;

    if (tid < NI) {
        int c = counts[b * NI + tid];
        inv[tid] = 1.0f / (float)(c > 1 ? c : 1);
    }
    // stage rows [w0, w1) of the map (16 B per thread-iteration, coalesced,
    // cached loads: neighbors' windows overlap ours in L2)
    {
        const int nb16 = ((w1 - w0) << 10) >> 4;
        const i32x4* src = (const i32x4*)(g8b + ((size_t)w0 << 10));
        i32x4* dst = (i32x4*)sg;
        for (int k = tid; k < nb16; k += 1024) dst[k] = src[k];
    }
    __syncthreads();

    const f32x4* ppb = (const f32x4*)(pp + (size_t)b * PB);
    const f32x4* dyb = (const f32x4*)(op + (size_t)b * 2 * PB);
    const f32x4* dxb = dyb + PB / 4;
    f32x4* pwb  = (f32x4*)(out + (size_t)b * PB);
    f32x4* owyb = (f32x4*)(out + (size_t)NB * PB + (size_t)b * 2 * PB);
    f32x4* owxb = owyb + PB / 4;

    const int qbase = bx * (BROWS * CDIM / 4);     // 4096 quads per block

    #pragma unroll 1
    for (int h = 0; h < 2; ++h) {                  // two halves: VGPR control
        const int q0 = qbase + 2048 * h + tid;     // quads q0, q0+1024

        f32x4 dyv[2], dxv[2], ppv[2];
        #pragma unroll
        for (int u = 0; u < 2; ++u) dyv[u] = __builtin_nontemporal_load(dyb + q0 + 1024 * u);
        #pragma unroll
        for (int u = 0; u < 2; ++u) dxv[u] = __builtin_nontemporal_load(dxb + q0 + 1024 * u);
        #pragma unroll
        for (int u = 0; u < 2; ++u) ppv[u] = __builtin_nontemporal_load(ppb + q0 + 1024 * u);

        // own map bytes from LDS (own rows always inside the window)
        uint32_t own[2];
        #pragma unroll
        for (int u = 0; u < 2; ++u) {
            const int pix = (q0 + 1024 * u) * 4;
            const int r = pix >> 10, c = pix & (CDIM - 1);
            own[u] = *(const uint32_t*)&sg[((r - w0) << 10) + c];
        }

        #pragma unroll
        for (int u = 0; u < 2; ++u) {
            const int   pix = (q0 + 1024 * u) * 4;
            const float rf  = (float)(pix >> 10);
            const float cf0 = (float)(pix & (CDIM - 1));
            f32x4 pwv, oyv, oxv;
            #pragma unroll
            for (int j = 0; j < 4; ++j) {
                const int gbyte = (own[u] >> (8 * j)) & 0xff;
                const int gs = gbyte & 0x7f;
                const int ms = gbyte >> 7;
                const float dy = dyv[u][j], dx = dxv[u][j];
                const float tyf = fminf(fmaxf(rintf(rf + dy), 0.0f), (float)(RDIM - 1));
                const float txf = fminf(fmaxf(rintf(cf0 + (float)j + dx), 0.0f), (float)(CDIM - 1));
                const int ty = (int)tyf, tx = (int)txf;
                int tg;
                if (ty >= w0 && ty < w1)
                    tg = sg[((ty - w0) << 10) + tx] & 0x7f;     // LDS gather
                else
                    tg = g8b[(ty << 10) + tx] & 0x7f;           // rare fallback
                const float w  = ms ? inv[gs] : 0.0f;
                const float aw = (ms && (tg == gs)) ? w : 0.0f;
                pwv[j] = w * (1.0f / (1.0f + __expf(-ppv[u][j])));
                oyv[j] = aw * dy;
                oxv[j] = aw * dx;
            }
            __builtin_nontemporal_store(pwv, pwb  + q0 + 1024 * u);
            __builtin_nontemporal_store(oyv, owyb + q0 + 1024 * u);
            __builtin_nontemporal_store(oxv, owxb + q0 + 1024 * u);
        }
    }
}

// ---------------------------------------------------------------------------
// Fallback (ws too small for the packed map): direct kernel.
// ---------------------------------------------------------------------------
__global__ __launch_bounds__(256) void cluster_plain_kernel(
    const float* __restrict__ pp, const float* __restrict__ op,
    const int* __restrict__ nz, const int* __restrict__ gt,
    const int* __restrict__ counts, float* __restrict__ out)
{
    __shared__ float inv[NI];
    const int b = blockIdx.y;
    if (threadIdx.x < NI) {
        int c = counts[b * NI + threadIdx.x];
        inv[threadIdx.x] = 1.0f / (float)(c > 1 ? c : 1);
    }
    __syncthreads();
    const int i = blockIdx.x * blockDim.x + threadIdx.x;

    const int*   gtb = gt + (size_t)b * PB;
    const int*   nzb = nz + (size_t)b * PB;
    const f32x4* ppb = (const f32x4*)(pp + (size_t)b * PB);
    const f32x4* dyb = (const f32x4*)(op + (size_t)b * 2 * PB);
    const f32x4* dxb = dyb + PB / 4;
    f32x4* pwb  = (f32x4*)(out + (size_t)b * PB);
    f32x4* owyb = (f32x4*)(out + (size_t)NB * PB + (size_t)b * 2 * PB);
    f32x4* owxb = owyb + PB / 4;

    const int   pix = i * 4;
    const float rf  = (float)(pix >> 10);
    const float cf0 = (float)(pix & (CDIM - 1));
    f32x4 ppv = ppb[i], dyv = dyb[i], dxv = dxb[i];
    i32x4 gv = *((const i32x4*)gtb + i), nzv = *((const i32x4*)nzb + i);

    f32x4 pwv, oyv, oxv;
    #pragma unroll
    for (int j = 0; j < 4; ++j) {
        const int gs = gv[j];
        const int ms = (nzv[j] > 0) & (gs > 0);
        float ty = fminf(fmaxf(rintf(rf + dyv[j]), 0.0f), (float)(RDIM - 1));
        float tx = fminf(fmaxf(rintf(cf0 + (float)j + dxv[j]), 0.0f), (float)(CDIM - 1));
        const int tg = gtb[(int)ty * CDIM + (int)tx];
        const float w  = ms ? inv[gs] : 0.0f;
        const float aw = (ms && (tg == gs)) ? w : 0.0f;
        pwv[j] = w * (1.0f / (1.0f + __expf(-ppv[j])));
        oyv[j] = aw * dyv[j];
        oxv[j] = aw * dxv[j];
    }
    pwb[i] = pwv; owyb[i] = oyv; owxb[i] = oxv;
}

extern "C" void kernel_launch(void* const* d_in, const int* in_sizes, int n_in,
                              void* d_out, int out_size, void* d_ws, size_t ws_size,
                              hipStream_t stream) {
    // setup_inputs order: non_zeros_map, pixel_pred, offset_pred, pixel_gt
    const int*   nz = (const int*)d_in[0];
    const float* pp = (const float*)d_in[1];
    const float* op = (const float*)d_in[2];
    const int*   gt = (const int*)d_in[3];
    float* out = (float*)d_out;

    int* counts = (int*)d_ws;                       // NB*NI ints at ws[0]
    const size_t need = 1024 + (size_t)NB * PB;     // counts (padded) + gt8 map
    const bool packed = ws_size >= need;
    uint8_t* gt8 = packed ? (uint8_t*)d_ws + 1024 : nullptr;

    hipMemsetAsync(counts, 0, NB * NI * sizeof(int), stream);

    dim3 blkA(256), grdA(256, NB);
    count_pack_kernel<<<grdA, blkA, 0, stream>>>(nz, gt, gt8, counts);

    if (packed) {
        cluster_lds_kernel<<<dim3(RDIM / BROWS, NB), dim3(1024), 0, stream>>>(pp, op, gt8, counts, out);
    } else {
        cluster_plain_kernel<<<dim3(1024, NB), dim3(256), 0, stream>>>(pp, op, nz, gt, counts, out);
    }
}

// Round 7
// 226.946 us; speedup vs baseline: 1.0411x; 1.0064x over previous
//
#include <hip/hip_runtime.h>
#include <cstdint>
#include <cstddef>

// FINAL CONFIG — best measured (R4: 227.46 us total). Revert from R6.
// Model: ~157 us fixed harness cost (restore+poison fills at 85% of write
// peak) + count_pack ~14 us (64 MB read floor x1.3) + cluster ~56 us
// (~4.4 TB/s combined demand BW ~= 70% of the copy recipe; invariant under
// MLP/gather-locality/tile-geometry changes across R2-R6 -> mixed-pattern
// machine limit for this access mix).

// Problem constants (match reference setup_inputs)
#define NB   8               // batch
#define RDIM 1024
#define CDIM 1024
#define PB   (RDIM * CDIM)   // pixels per batch = 1M
#define NI   16              // MAX_INSTANCES

// Cluster-kernel geometry: 1024-thread blocks, 8 rows/block, LDS-staged
// gather window of 8 + 2*26 = 60 rows (61440 B). Margin 26 covers |offset|
// up to 26 px; N(0,4) offsets max ~23 over 8.4M samples; larger offsets take
// the (execz-skipped) global fallback, so correctness holds for any input.
#define MARG  26
#define BROWS 8
#define WROWS (BROWS + 2 * MARG)   // 60

typedef int     i32x4 __attribute__((ext_vector_type(4)));
typedef float   f32x4 __attribute__((ext_vector_type(4)));
typedef uint8_t u8x4  __attribute__((ext_vector_type(4)));

// ---------------------------------------------------------------------------
// Kernel A: per-(batch,instance) valid-pixel histogram via wave-ballot
// popcount (no per-pixel atomics; R1's LDS-atomic version cost ~21 us, this
// runs ~14 us) + pack gt|mask into a uint8 map (8 MB) so the main pass reads
// 8 MB instead of 64 MB and gathers bytes instead of int32.
// ---------------------------------------------------------------------------
__global__ __launch_bounds__(256) void count_pack_kernel(
    const int* __restrict__ nz, const int* __restrict__ gt,
    uint8_t* __restrict__ gt8, int* __restrict__ counts)
{
    __shared__ unsigned s[4 * NI];           // 4 waves x 16 bins
    const int b    = blockIdx.y;
    const int lane = threadIdx.x & 63;
    const int wv   = threadIdx.x >> 6;
    const i32x4* nzb = (const i32x4*)(nz + (size_t)b * PB);
    const i32x4* gtb = (const i32x4*)(gt + (size_t)b * PB);
    u8x4* g8b = gt8 ? (u8x4*)(gt8 + (size_t)b * PB) : nullptr;

    unsigned wc[NI];
    #pragma unroll
    for (int k = 0; k < NI; ++k) wc[k] = 0;

    const int n4 = PB / 4;
    for (int i = blockIdx.x * blockDim.x + threadIdx.x; i < n4;
         i += gridDim.x * blockDim.x) {
        i32x4 nzv = __builtin_nontemporal_load(&nzb[i]);
        i32x4 gv  = __builtin_nontemporal_load(&gtb[i]);
        int gm[4];
        u8x4 o;
        #pragma unroll
        for (int j = 0; j < 4; ++j) {
            const int g = gv[j];
            const int m = (nzv[j] > 0) & (g > 0);
            gm[j] = m ? g : 0;                       // 0 = contributes nowhere
            o[j]  = (uint8_t)(g | (m << 7));
        }
        if (g8b) g8b[i] = o;                          // cached store (B re-reads)
        #pragma unroll
        for (int j = 0; j < 4; ++j) {
            #pragma unroll
            for (int id = 1; id < NI; ++id) {
                unsigned long long bal = __ballot(gm[j] == id);
                wc[id] += (unsigned)__popcll(bal);    // wave-uniform scalar add
            }
        }
    }
    if (lane == 0) {
        #pragma unroll
        for (int id = 1; id < NI; ++id) s[wv * NI + id] = wc[id];
    }
    __syncthreads();
    if (threadIdx.x >= 1 && threadIdx.x < NI) {
        unsigned sum = s[threadIdx.x] + s[NI + threadIdx.x] +
                       s[2 * NI + threadIdx.x] + s[3 * NI + threadIdx.x];
        if (sum) atomicAdd((unsigned*)&counts[b * NI + threadIdx.x], sum);
    }
}

// ---------------------------------------------------------------------------
// Kernel B (packed path): LDS-staged gather + NT streaming (best measured).
//  - block = 1024 threads, owns 8 consecutive rows (2048 quads, 2/thread)
//  - 60-row gt8 window in LDS; gathers are ds_read_u8 (random-addr ~2-way
//    bank aliasing is free per m136) instead of 64-line L1 probes
//  - own-pixel map bytes also come from LDS
//  - out-of-window targets take a predicated global fallback (execz-skipped)
//  - NT loads/stores on the 192 MB of streamed traffic (measured ~8 us
//    better than plain cached — R4 vs R5 A/B)
//  - XCD band swizzle keeps overlapping windows on one XCD's L2
// rintf == round-half-to-even == np.round (critical for `agree` parity).
// ---------------------------------------------------------------------------
__global__ __launch_bounds__(1024, 8) void cluster_lds_kernel(
    const float* __restrict__ pp, const float* __restrict__ op,
    const uint8_t* __restrict__ gt8,
    const int* __restrict__ counts, float* __restrict__ out)
{
    __shared__ __align__(16) uint8_t sg[WROWS * CDIM];   // 61440 B
    __shared__ float inv[NI];

    const int b   = blockIdx.y;
    const int tid = threadIdx.x;

    // XCD band swizzle (gridDim.x = 128, 8 XCDs -> 16-block bands)
    const int nbx = gridDim.x;
    const int p0  = blockIdx.x;
    const int bx  = (p0 & 7) * (nbx >> 3) + (p0 >> 3);

    const int r0 = bx * BROWS;
    const int w0 = (r0 - MARG) > 0 ? (r0 - MARG) : 0;
    int w1 = r0 + BROWS + MARG; if (w1 > RDIM) w1 = RDIM;

    const uint8_t* g8b = gt8 + (size_t)b * PB;

    if (tid < NI) {
        int c = counts[b * NI + tid];
        inv[tid] = 1.0f / (float)(c > 1 ? c : 1);
    }
    // stage rows [w0, w1) of the map (16 B per thread-iteration, coalesced,
    // cached loads: neighbors' windows overlap ours in L2)
    {
        const int nb16 = ((w1 - w0) << 10) >> 4;
        const i32x4* src = (const i32x4*)(g8b + ((size_t)w0 << 10));
        i32x4* dst = (i32x4*)sg;
        for (int k = tid; k < nb16; k += 1024) dst[k] = src[k];
    }
    __syncthreads();

    const f32x4* ppb = (const f32x4*)(pp + (size_t)b * PB);
    const f32x4* dyb = (const f32x4*)(op + (size_t)b * 2 * PB);
    const f32x4* dxb = dyb + PB / 4;
    f32x4* pwb  = (f32x4*)(out + (size_t)b * PB);
    f32x4* owyb = (f32x4*)(out + (size_t)NB * PB + (size_t)b * 2 * PB);
    f32x4* owxb = owyb + PB / 4;

    const int q0 = bx * (BROWS * CDIM / 4) + tid;   // first of 2 quads

    // issue all streaming loads up front
    f32x4 dyv[2], dxv[2], ppv[2];
    #pragma unroll
    for (int u = 0; u < 2; ++u) dyv[u] = __builtin_nontemporal_load(dyb + q0 + 1024 * u);
    #pragma unroll
    for (int u = 0; u < 2; ++u) dxv[u] = __builtin_nontemporal_load(dxb + q0 + 1024 * u);
    #pragma unroll
    for (int u = 0; u < 2; ++u) ppv[u] = __builtin_nontemporal_load(ppb + q0 + 1024 * u);

    // own map bytes from LDS (own rows are always inside the window)
    uint32_t own[2];
    #pragma unroll
    for (int u = 0; u < 2; ++u) {
        const int pix = (q0 + 1024 * u) * 4;
        const int r = pix >> 10, c = pix & (CDIM - 1);
        own[u] = *(const uint32_t*)&sg[((r - w0) << 10) + c];
    }

    #pragma unroll
    for (int u = 0; u < 2; ++u) {
        const int   pix = (q0 + 1024 * u) * 4;
        const float rf  = (float)(pix >> 10);
        const float cf0 = (float)(pix & (CDIM - 1));
        f32x4 pwv, oyv, oxv;
        #pragma unroll
        for (int j = 0; j < 4; ++j) {
            const int gbyte = (own[u] >> (8 * j)) & 0xff;
            const int gs = gbyte & 0x7f;
            const int ms = gbyte >> 7;
            const float dy = dyv[u][j], dx = dxv[u][j];
            const float tyf = fminf(fmaxf(rintf(rf + dy), 0.0f), (float)(RDIM - 1));
            const float txf = fminf(fmaxf(rintf(cf0 + (float)j + dx), 0.0f), (float)(CDIM - 1));
            const int ty = (int)tyf, tx = (int)txf;
            int tg;
            if (ty >= w0 && ty < w1)
                tg = sg[((ty - w0) << 10) + tx] & 0x7f;     // LDS gather
            else
                tg = g8b[(ty << 10) + tx] & 0x7f;           // rare fallback
            const float w  = ms ? inv[gs] : 0.0f;
            const float aw = (ms && (tg == gs)) ? w : 0.0f;
            pwv[j] = w * (1.0f / (1.0f + __expf(-ppv[u][j])));
            oyv[j] = aw * dy;
            oxv[j] = aw * dx;
        }
        __builtin_nontemporal_store(pwv, pwb  + q0 + 1024 * u);
        __builtin_nontemporal_store(oyv, owyb + q0 + 1024 * u);
        __builtin_nontemporal_store(oxv, owxb + q0 + 1024 * u);
    }
}

// ---------------------------------------------------------------------------
// Fallback (ws too small for the packed map): direct kernel.
// ---------------------------------------------------------------------------
__global__ __launch_bounds__(256) void cluster_plain_kernel(
    const float* __restrict__ pp, const float* __restrict__ op,
    const int* __restrict__ nz, const int* __restrict__ gt,
    const int* __restrict__ counts, float* __restrict__ out)
{
    __shared__ float inv[NI];
    const int b = blockIdx.y;
    if (threadIdx.x < NI) {
        int c = counts[b * NI + threadIdx.x];
        inv[threadIdx.x] = 1.0f / (float)(c > 1 ? c : 1);
    }
    __syncthreads();
    const int i = blockIdx.x * blockDim.x + threadIdx.x;

    const int*   gtb = gt + (size_t)b * PB;
    const int*   nzb = nz + (size_t)b * PB;
    const f32x4* ppb = (const f32x4*)(pp + (size_t)b * PB);
    const f32x4* dyb = (const f32x4*)(op + (size_t)b * 2 * PB);
    const f32x4* dxb = dyb + PB / 4;
    f32x4* pwb  = (f32x4*)(out + (size_t)b * PB);
    f32x4* owyb = (f32x4*)(out + (size_t)NB * PB + (size_t)b * 2 * PB);
    f32x4* owxb = owyb + PB / 4;

    const int   pix = i * 4;
    const float rf  = (float)(pix >> 10);
    const float cf0 = (float)(pix & (CDIM - 1));
    f32x4 ppv = ppb[i], dyv = dyb[i], dxv = dxb[i];
    i32x4 gv = *((const i32x4*)gtb + i), nzv = *((const i32x4*)nzb + i);

    f32x4 pwv, oyv, oxv;
    #pragma unroll
    for (int j = 0; j < 4; ++j) {
        const int gs = gv[j];
        const int ms = (nzv[j] > 0) & (gs > 0);
        float ty = fminf(fmaxf(rintf(rf + dyv[j]), 0.0f), (float)(RDIM - 1));
        float tx = fminf(fmaxf(rintf(cf0 + (float)j + dxv[j]), 0.0f), (float)(CDIM - 1));
        const int tg = gtb[(int)ty * CDIM + (int)tx];
        const float w  = ms ? inv[gs] : 0.0f;
        const float aw = (ms && (tg == gs)) ? w : 0.0f;
        pwv[j] = w * (1.0f / (1.0f + __expf(-ppv[j])));
        oyv[j] = aw * dyv[j];
        oxv[j] = aw * dxv[j];
    }
    pwb[i] = pwv; owyb[i] = oyv; owxb[i] = oxv;
}

extern "C" void kernel_launch(void* const* d_in, const int* in_sizes, int n_in,
                              void* d_out, int out_size, void* d_ws, size_t ws_size,
                              hipStream_t stream) {
    // setup_inputs order: non_zeros_map, pixel_pred, offset_pred, pixel_gt
    const int*   nz = (const int*)d_in[0];
    const float* pp = (const float*)d_in[1];
    const float* op = (const float*)d_in[2];
    const int*   gt = (const int*)d_in[3];
    float* out = (float*)d_out;

    int* counts = (int*)d_ws;                       // NB*NI ints at ws[0]
    const size_t need = 1024 + (size_t)NB * PB;     // counts (padded) + gt8 map
    const bool packed = ws_size >= need;
    uint8_t* gt8 = packed ? (uint8_t*)d_ws + 1024 : nullptr;

    hipMemsetAsync(counts, 0, NB * NI * sizeof(int), stream);

    dim3 blkA(256), grdA(256, NB);
    count_pack_kernel<<<grdA, blkA, 0, stream>>>(nz, gt, gt8, counts);

    if (packed) {
        cluster_lds_kernel<<<dim3(128, NB), dim3(1024), 0, stream>>>(pp, op, gt8, counts, out);
    } else {
        cluster_plain_kernel<<<dim3(1024, NB), dim3(256), 0, stream>>>(pp, op, nz, gt, counts, out);
    }
}